// Round 9
// baseline (243.172 us; speedup 1.0000x reference)
//
#include <hip/hip_runtime.h>

// MHA forward, B=2, S=2048, D=1024, H=16, Dk=64, causal, RoPE. fp32 I/O.
// Internal bf16 MFMA 16x16x32, fp32 accum.
// R9: (a) GEMMs rebuilt on the m97 pattern: __builtin_amdgcn_global_load_lds
// width=16 staging (no VGPR round-trip), unpadded LDS rows with XOR unit
// swizzle (lane-contiguous DMA dest + 2-way-max ds_read_b128), 2-barrier
// K-loop, XCD-aware block swizzle; 128x128 tiles for QKV, 128x64 for
// out-proj (512 blocks = 2/CU). (b) attn V-transpose: 2-row/8-col threads,
// packed b32 writes -> conflict-free, no swizzle.

typedef unsigned short u16;
typedef __attribute__((ext_vector_type(8))) short short8;   // 8 bf16 = 4 VGPRs
typedef __attribute__((ext_vector_type(4))) float float4v;  // MFMA C/D

typedef const __attribute__((address_space(1))) void GV;    // global
typedef __attribute__((address_space(3))) void LV;          // LDS

#define VSTR 72   // attn Vt/Ps row stride (u16): 144B rows, 2-way read banks
#define QSCL 0.18033688011112042f   // 0.125 * log2(e)

__device__ __forceinline__ u16 f2b(float f) {
    union { float f; unsigned int i; } t; t.f = f;
    unsigned int r = t.i + 0x7fffu + ((t.i >> 16) & 1u);   // RNE
    return (u16)(r >> 16);
}

// ---------------- fused fp32 -> bf16 converter ------------------------------
__global__ __launch_bounds__(256) void cvt_all(
    const float4* __restrict__ x,  const float4* __restrict__ wq,
    const float4* __restrict__ wk, const float4* __restrict__ wv,
    const float4* __restrict__ wo,
    u16* __restrict__ xb, u16* __restrict__ wcat, u16* __restrict__ wob)
{
    const int i = blockIdx.x * 256 + threadIdx.x;
    const float4* s; u16* d; int off;
    if (i < 524288) { s = x; d = xb; off = i; }
    else {
        const int widx = i - 524288;
        const int w = widx >> 17, o = widx & 131071;
        switch (w) {
            case 0:  s = wq; d = wcat;              break;
            case 1:  s = wk; d = wcat + (1 << 20);  break;
            case 2:  s = wv; d = wcat + (2 << 20);  break;
            default: s = wo; d = wob;               break;
        }
        off = o;
    }
    float4 a = s[2 * off], b = s[2 * off + 1];
    u16 t[8] = {f2b(a.x), f2b(a.y), f2b(a.z), f2b(a.w),
                f2b(b.x), f2b(b.y), f2b(b.z), f2b(b.w)};
    reinterpret_cast<int4*>(d)[off] = *reinterpret_cast<int4*>(t);
}

// ---------------------------------------------------------------------------
// Y[m][n] = sum_k X[m][k] * W[n][k]; 128(m) x NT*32(n) x 64(k) tiles.
// Staging: global_load_lds width=16. LDS layout: 64-elem rows (128B),
// 16B unit u stored at phys u^(row&7) -> DMA dest lane-contiguous AND
// ds_read_b128 2-way max. ROPE=1: route cols to Yq/Yk/Yv, RoPE q,k, scale q.
// XCD swizzle: block g -> xcd=g&7 owns m-strips [xcd*4, xcd*4+4).
// ---------------------------------------------------------------------------
template<int NT, int ROPE, int NBLK>
__global__ __launch_bounds__(256) void gemm_tile(
    const u16* __restrict__ X, const u16* __restrict__ Wb,
    u16* __restrict__ Yq, u16* __restrict__ Yk, u16* __restrict__ Yv,
    float* __restrict__ Yf)
{
    __shared__ u16 As[128 * 64];
    __shared__ u16 Bs[NT * 32 * 64];

    const int tid  = threadIdx.x;
    const int wave = tid >> 6;
    const int lane = tid & 63;
    const int quad = lane >> 4;
    const int l16  = lane & 15;
    const int wm = (wave >> 1) * 64, wn = (wave & 1) * (NT * 16);
    const int g = blockIdx.x;
    const int rr = g >> 3;
    const int m0 = ((g & 7) * 4 + rr / NBLK) * 128;
    const int n0 = (rr % NBLK) * (NT * 32);
    const int lrow = lane >> 3;                         // 0..7 within 8-row slab
    const int cg8  = (lane & 7) ^ lrow;                 // swizzled global unit

    float4v acc[4][NT];
#pragma unroll
    for (int mt = 0; mt < 4; mt++)
#pragma unroll
        for (int nt = 0; nt < NT; nt++) acc[mt][nt] = (float4v){0.f, 0.f, 0.f, 0.f};

    for (int kb = 0; kb < 1024; kb += 64) {
        __syncthreads();                                 // prev reads done
#pragma unroll
        for (int t = 0; t < 4; t++) {                    // stage A: 4x 1KB/wave
            const int I = wave * 4 + t;
            const u16* gp = X + (size_t)(m0 + I * 8 + lrow) * 1024 + kb + cg8 * 8;
            __builtin_amdgcn_global_load_lds((GV*)gp, (LV*)&As[I * 512], 16, 0, 0);
        }
#pragma unroll
        for (int t = 0; t < NT; t++) {                   // stage B: NTx 1KB/wave
            const int I = wave * NT + t;
            const u16* gp = Wb + (size_t)(n0 + I * 8 + lrow) * 1024 + kb + cg8 * 8;
            __builtin_amdgcn_global_load_lds((GV*)gp, (LV*)&Bs[I * 512], 16, 0, 0);
        }
        __syncthreads();                                 // vmcnt drained here
#pragma unroll
        for (int ks = 0; ks < 2; ks++) {
            const int su = ((ks * 4 + quad) ^ (l16 & 7)) * 8;   // swizzled unit
            short8 af[4], bf[NT];
#pragma unroll
            for (int t = 0; t < 4; t++)
                af[t] = *reinterpret_cast<const short8*>(&As[(wm + t * 16 + l16) * 64 + su]);
#pragma unroll
            for (int t = 0; t < NT; t++)
                bf[t] = *reinterpret_cast<const short8*>(&Bs[(wn + t * 16 + l16) * 64 + su]);
#pragma unroll
            for (int mt = 0; mt < 4; mt++)
#pragma unroll
                for (int nt = 0; nt < NT; nt++)
                    acc[mt][nt] = __builtin_amdgcn_mfma_f32_16x16x32_bf16(af[mt], bf[nt], acc[mt][nt], 0, 0, 0);
        }
    }

    if (ROPE) {
#pragma unroll
        for (int nt = 0; nt < NT; nt++) {
            const int cg = n0 + wn + nt * 16 + l16;      // global col 0..3071
            const int buf = cg >> 10;                    // 0=q 1=k 2=v
            const int c = cg & 1023;
            u16* dst = (buf == 0) ? Yq : ((buf == 1) ? Yk : Yv);
            const bool rp = (buf < 2);
            const float scl = (buf == 0) ? QSCL : 1.0f;
            float freq = 0.f;
            if (rp) freq = exp2f((float)((cg & 63) >> 1) * -0.4152410118609203f);
#pragma unroll
            for (int mt = 0; mt < 4; mt++)
#pragma unroll
                for (int r = 0; r < 4; r++) {
                    const int row = m0 + wm + mt * 16 + quad * 4 + r;
                    float v = acc[mt][nt][r];
                    if (rp) {
                        float sn, cs; sincosf((float)(row & 2047) * freq, &sn, &cs);
                        const float partner = __shfl_xor(v, 1);
                        v = (l16 & 1) ? fmaf(v, cs,  partner * sn)
                                      : fmaf(v, cs, -partner * sn);
                    }
                    dst[(size_t)row * 1024 + c] = f2b(v * scl);
                }
        }
    } else {
#pragma unroll
        for (int nt = 0; nt < NT; nt++) {
            const int col = n0 + wn + nt * 16 + l16;
#pragma unroll
            for (int mt = 0; mt < 4; mt++)
#pragma unroll
                for (int r = 0; r < 4; r++) {
                    const int row = m0 + wm + mt * 16 + quad * 4 + r;
                    Yf[(size_t)row * 1024 + col] = acc[mt][nt][r];
                }
        }
    }
}

// ---------------------------------------------------------------------------
// Flash causal attention, paired q-tiles (qtA, 31-qtA), unnormalized softmax
// (q pre-scaled 0.125*log2e -> p = exp2f(s)). K frags direct from global,
// prefetched. V transposed into LDS via 2-row/8-col threads + packed b32
// writes (conflict-free). O aliases Q (block-disjoint regions).
// ---------------------------------------------------------------------------
__global__ __launch_bounds__(256, 2) void attn_kernel(
    const u16* Q, const u16* __restrict__ K,
    const u16* __restrict__ V, u16* O)
{
    __shared__ u16 Vt[64 * VSTR];           // Vt[d][s]
    __shared__ u16 Ps[4 * 16 * VSTR];

    const int tid  = threadIdx.x;
    const int wave = tid >> 6;
    const int lane = tid & 63;
    const int quad = lane >> 4;
    const int l16  = lane & 15;
    const int qtA = blockIdx.x;             // 0..15
    const int qtB = 31 - qtA;               // 31..16
    const int h = blockIdx.y, b = blockIdx.z;
    const size_t base = ((size_t)b * 2048) * 1024 + (size_t)h * 64;

    short8 qfA[2], qfB[2];
    {
        const size_t ra = base + (size_t)(qtA * 64 + wave * 16 + l16) * 1024;
        qfA[0] = *reinterpret_cast<const short8*>(Q + ra + quad * 8);
        qfA[1] = *reinterpret_cast<const short8*>(Q + ra + 32 + quad * 8);
        const size_t rb = base + (size_t)(qtB * 64 + wave * 16 + l16) * 1024;
        qfB[0] = *reinterpret_cast<const short8*>(Q + rb + quad * 8);
        qfB[1] = *reinterpret_cast<const short8*>(Q + rb + 32 + quad * 8);
    }

    float4v oA[4], oB[4];
#pragma unroll
    for (int i = 0; i < 4; i++) { oA[i] = (float4v){0.f,0.f,0.f,0.f}; oB[i] = (float4v){0.f,0.f,0.f,0.f}; }
    float sA[4] = {0.f,0.f,0.f,0.f}, sB[4] = {0.f,0.f,0.f,0.f};

    u16* Pw = Ps + wave * 16 * VSTR;
    const int s0 = (tid & 31) * 2;          // V staging: two s-rows
    const int d0 = (tid >> 5) * 8;          // 8 d-cols

    // prefetch tile j=0
    const u16* Vp = V + base + (size_t)s0 * 1024 + d0;
    const u16* kbase = K + base + (size_t)l16 * 1024 + quad * 8;
    int4 vr0 = *reinterpret_cast<const int4*>(Vp);
    int4 vr1 = *reinterpret_cast<const int4*>(Vp + 1024);
    short8 kn[4][2], kc[4][2], vf[4][2];
#pragma unroll
    for (int nt = 0; nt < 4; nt++)
#pragma unroll
        for (int ks = 0; ks < 2; ks++)
            kn[nt][ks] = *reinterpret_cast<const short8*>(kbase + (size_t)(nt * 16) * 1024 + ks * 32);

    auto proc = [&](const short8 (&qf)[2], float4v (&oc)[4], float (&sr)[4], bool diag) {
        float4v sacc[4];
#pragma unroll
        for (int nt = 0; nt < 4; nt++) {
            sacc[nt] = (float4v){0.f, 0.f, 0.f, 0.f};
#pragma unroll
            for (int ks = 0; ks < 2; ks++)
                sacc[nt] = __builtin_amdgcn_mfma_f32_16x16x32_bf16(qf[ks], kc[nt][ks], sacc[nt], 0, 0, 0);
        }
#pragma unroll
        for (int r = 0; r < 4; r++) {
            const int qloc = wave * 16 + quad * 4 + r;
#pragma unroll
            for (int nt = 0; nt < 4; nt++) {
                float s = sacc[nt][r];                       // log2-domain
                if (diag && (nt * 16 + l16 > qloc)) s = -1e30f;
                const float p = exp2f(s);                    // masked -> 0
                sr[r] += p;
                Pw[(quad * 4 + r) * VSTR + nt * 16 + l16] = f2b(p);
            }
        }
        __builtin_amdgcn_wave_barrier();   // P write->read is wave-local
#pragma unroll
        for (int ks = 0; ks < 2; ks++) {
            short8 pf = *reinterpret_cast<const short8*>(&Pw[l16 * VSTR + ks * 32 + quad * 8]);
#pragma unroll
            for (int dt = 0; dt < 4; dt++)
                oc[dt] = __builtin_amdgcn_mfma_f32_16x16x32_bf16(pf, vf[dt][ks], oc[dt], 0, 0, 0);
        }
        __builtin_amdgcn_wave_barrier();
    };

    for (int j = 0; j <= qtB; j++) {
        __syncthreads();   // all waves done reading previous Vt
        {
            const u16* a = reinterpret_cast<const u16*>(&vr0);   // V[s0][d0..+7]
            const u16* c = reinterpret_cast<const u16*>(&vr1);   // V[s0+1][d0..+7]
#pragma unroll
            for (int e = 0; e < 8; e++) {
                const unsigned int pk = (unsigned int)a[e] | ((unsigned int)c[e] << 16);
                *reinterpret_cast<unsigned int*>(&Vt[(d0 + e) * VSTR + s0]) = pk;
            }
        }
#pragma unroll
        for (int nt = 0; nt < 4; nt++)
#pragma unroll
            for (int ks = 0; ks < 2; ks++) kc[nt][ks] = kn[nt][ks];
        __syncthreads();
        if (j < qtB) {     // prefetch tile j+1; latency hidden by procs
            Vp += 65536;
            vr0 = *reinterpret_cast<const int4*>(Vp);
            vr1 = *reinterpret_cast<const int4*>(Vp + 1024);
            const u16* kb2 = kbase + (size_t)(j + 1) * 65536;
#pragma unroll
            for (int nt = 0; nt < 4; nt++)
#pragma unroll
                for (int ks = 0; ks < 2; ks++)
                    kn[nt][ks] = *reinterpret_cast<const short8*>(kb2 + (size_t)(nt * 16) * 1024 + ks * 32);
        }
#pragma unroll
        for (int nt = 0; nt < 4; nt++)
#pragma unroll
            for (int ks = 0; ks < 2; ks++)
                vf[nt][ks] = *reinterpret_cast<const short8*>(&Vt[(nt * 16 + l16) * VSTR + ks * 32 + quad * 8]);
        if (j <= qtA) proc(qfA, oA, sA, j == qtA);
        proc(qfB, oB, sB, j == qtB);
    }

    // epilogue: one cross-lane sum reduction, normalize, write
#pragma unroll
    for (int r = 0; r < 4; r++) {
        float la = sA[r], lb = sB[r];
#pragma unroll
        for (int msk = 1; msk < 16; msk <<= 1) { la += __shfl_xor(la, msk); lb += __shfl_xor(lb, msk); }
        const float invA = 1.0f / la, invB = 1.0f / lb;
        const int rloc = wave * 16 + quad * 4 + r;
        const size_t rowA = base + (size_t)(qtA * 64 + rloc) * 1024;
        const size_t rowB = base + (size_t)(qtB * 64 + rloc) * 1024;
#pragma unroll
        for (int dt = 0; dt < 4; dt++) {
            O[rowA + dt * 16 + l16] = f2b(oA[dt][r] * invA);
            O[rowB + dt * 16 + l16] = f2b(oB[dt][r] * invB);
        }
    }
}

// ---------------------------------------------------------------------------
extern "C" void kernel_launch(void* const* d_in, const int* in_sizes, int n_in,
                              void* d_out, int out_size, void* d_ws, size_t ws_size,
                              hipStream_t stream) {
    (void)in_sizes; (void)n_in; (void)out_size; (void)ws_size;
    const float* x  = (const float*)d_in[0];
    const float* wq = (const float*)d_in[1];
    const float* wk = (const float*)d_in[2];
    const float* wv = (const float*)d_in[3];
    const float* wo = (const float*)d_in[4];

    const size_t MN = (size_t)4096 * 1024;

    // d_out (16MB) hosts xb (8MB) + wcat (6MB) until the final fp32 write.
    u16* xb   = (u16*)d_out;
    u16* wcat = xb + MN;                    // [3072][1024] = wq|wk|wv rows
    u16* qbuf = (u16*)d_ws;                 // also attention output
    u16* kbuf = qbuf + MN;
    u16* vbuf = kbuf + MN;
    u16* wob  = vbuf + MN;                  // ws total: 26MB

    cvt_all<<<4096, 256, 0, stream>>>((const float4*)x, (const float4*)wq,
                                      (const float4*)wk, (const float4*)wv,
                                      (const float4*)wo, xb, wcat, wob);
    gemm_tile<4, 1, 24><<<768, 256, 0, stream>>>(xb, wcat, qbuf, kbuf, vbuf, nullptr);
    attn_kernel<<<dim3(16, 16, 2), 256, 0, stream>>>(qbuf, kbuf, vbuf, qbuf);
    gemm_tile<2, 0, 16><<<512, 256, 0, stream>>>(qbuf, wob, nullptr, nullptr, nullptr, (float*)d_out);
}

// Round 10
// 233.721 us; speedup vs baseline: 1.0404x; 1.0404x over previous
//
#include <hip/hip_runtime.h>

// MHA forward, B=2, S=2048, D=1024, H=16, Dk=64, causal, RoPE. fp32 I/O.
// Internal bf16 MFMA 16x16x32, fp32 accum.
// R10: revert attn V staging to R8's coalesced loads + swizzled LDS writes
// (R9's "conflict-free" variant destroyed global coalescing: lane-stride
// 4KB gathers, +15us). Add XCD grouping: the 16 blocks sharing one (b,h)'s
// 512KB K/V land on one XCD (g = slot*8 + xcd round-robin heuristic).
// GEMMs unchanged from R9 (m97 global_load_lds pattern).

typedef unsigned short u16;
typedef __attribute__((ext_vector_type(8))) short short8;   // 8 bf16 = 4 VGPRs
typedef __attribute__((ext_vector_type(4))) float float4v;  // MFMA C/D

typedef const __attribute__((address_space(1))) void GV;    // global
typedef __attribute__((address_space(3))) void LV;          // LDS

#define VSTR 72   // attn Vt/Ps row stride (u16): 144B rows, 2-way read banks
#define QSCL 0.18033688011112042f   // 0.125 * log2(e)

__device__ __forceinline__ u16 f2b(float f) {
    union { float f; unsigned int i; } t; t.f = f;
    unsigned int r = t.i + 0x7fffu + ((t.i >> 16) & 1u);   // RNE
    return (u16)(r >> 16);
}

// ---------------- fused fp32 -> bf16 converter ------------------------------
__global__ __launch_bounds__(256) void cvt_all(
    const float4* __restrict__ x,  const float4* __restrict__ wq,
    const float4* __restrict__ wk, const float4* __restrict__ wv,
    const float4* __restrict__ wo,
    u16* __restrict__ xb, u16* __restrict__ wcat, u16* __restrict__ wob)
{
    const int i = blockIdx.x * 256 + threadIdx.x;
    const float4* s; u16* d; int off;
    if (i < 524288) { s = x; d = xb; off = i; }
    else {
        const int widx = i - 524288;
        const int w = widx >> 17, o = widx & 131071;
        switch (w) {
            case 0:  s = wq; d = wcat;              break;
            case 1:  s = wk; d = wcat + (1 << 20);  break;
            case 2:  s = wv; d = wcat + (2 << 20);  break;
            default: s = wo; d = wob;               break;
        }
        off = o;
    }
    float4 a = s[2 * off], b = s[2 * off + 1];
    u16 t[8] = {f2b(a.x), f2b(a.y), f2b(a.z), f2b(a.w),
                f2b(b.x), f2b(b.y), f2b(b.z), f2b(b.w)};
    reinterpret_cast<int4*>(d)[off] = *reinterpret_cast<int4*>(t);
}

// ---------------------------------------------------------------------------
// Y[m][n] = sum_k X[m][k] * W[n][k]; 128(m) x NT*32(n) x 64(k) tiles.
// Staging: global_load_lds width=16. LDS: 64-elem rows, 16B unit u stored at
// phys u^(row&7) (lane-contiguous DMA dest, swizzled ds_read_b128).
// ROPE=1: route cols to Yq/Yk/Yv, RoPE q,k, scale q by QSCL.
// XCD swizzle: block g -> xcd=g&7 owns m-strips [xcd*4, xcd*4+4).
// ---------------------------------------------------------------------------
template<int NT, int ROPE, int NBLK>
__global__ __launch_bounds__(256) void gemm_tile(
    const u16* __restrict__ X, const u16* __restrict__ Wb,
    u16* __restrict__ Yq, u16* __restrict__ Yk, u16* __restrict__ Yv,
    float* __restrict__ Yf)
{
    __shared__ u16 As[128 * 64];
    __shared__ u16 Bs[NT * 32 * 64];

    const int tid  = threadIdx.x;
    const int wave = tid >> 6;
    const int lane = tid & 63;
    const int quad = lane >> 4;
    const int l16  = lane & 15;
    const int wm = (wave >> 1) * 64, wn = (wave & 1) * (NT * 16);
    const int g = blockIdx.x;
    const int rr = g >> 3;
    const int m0 = ((g & 7) * 4 + rr / NBLK) * 128;
    const int n0 = (rr % NBLK) * (NT * 32);
    const int lrow = lane >> 3;                         // 0..7 within 8-row slab
    const int cg8  = (lane & 7) ^ lrow;                 // swizzled global unit

    float4v acc[4][NT];
#pragma unroll
    for (int mt = 0; mt < 4; mt++)
#pragma unroll
        for (int nt = 0; nt < NT; nt++) acc[mt][nt] = (float4v){0.f, 0.f, 0.f, 0.f};

    for (int kb = 0; kb < 1024; kb += 64) {
        __syncthreads();                                 // prev reads done
#pragma unroll
        for (int t = 0; t < 4; t++) {                    // stage A: 4x 1KB/wave
            const int I = wave * 4 + t;
            const u16* gp = X + (size_t)(m0 + I * 8 + lrow) * 1024 + kb + cg8 * 8;
            __builtin_amdgcn_global_load_lds((GV*)gp, (LV*)&As[I * 512], 16, 0, 0);
        }
#pragma unroll
        for (int t = 0; t < NT; t++) {                   // stage B: NTx 1KB/wave
            const int I = wave * NT + t;
            const u16* gp = Wb + (size_t)(n0 + I * 8 + lrow) * 1024 + kb + cg8 * 8;
            __builtin_amdgcn_global_load_lds((GV*)gp, (LV*)&Bs[I * 512], 16, 0, 0);
        }
        __syncthreads();                                 // vmcnt drained here
#pragma unroll
        for (int ks = 0; ks < 2; ks++) {
            const int su = ((ks * 4 + quad) ^ (l16 & 7)) * 8;   // swizzled unit
            short8 af[4], bf[NT];
#pragma unroll
            for (int t = 0; t < 4; t++)
                af[t] = *reinterpret_cast<const short8*>(&As[(wm + t * 16 + l16) * 64 + su]);
#pragma unroll
            for (int t = 0; t < NT; t++)
                bf[t] = *reinterpret_cast<const short8*>(&Bs[(wn + t * 16 + l16) * 64 + su]);
#pragma unroll
            for (int mt = 0; mt < 4; mt++)
#pragma unroll
                for (int nt = 0; nt < NT; nt++)
                    acc[mt][nt] = __builtin_amdgcn_mfma_f32_16x16x32_bf16(af[mt], bf[nt], acc[mt][nt], 0, 0, 0);
        }
    }

    if (ROPE) {
#pragma unroll
        for (int nt = 0; nt < NT; nt++) {
            const int cg = n0 + wn + nt * 16 + l16;      // global col 0..3071
            const int buf = cg >> 10;                    // 0=q 1=k 2=v
            const int c = cg & 1023;
            u16* dst = (buf == 0) ? Yq : ((buf == 1) ? Yk : Yv);
            const bool rp = (buf < 2);
            const float scl = (buf == 0) ? QSCL : 1.0f;
            float freq = 0.f;
            if (rp) freq = exp2f((float)((cg & 63) >> 1) * -0.4152410118609203f);
#pragma unroll
            for (int mt = 0; mt < 4; mt++)
#pragma unroll
                for (int r = 0; r < 4; r++) {
                    const int row = m0 + wm + mt * 16 + quad * 4 + r;
                    float v = acc[mt][nt][r];
                    if (rp) {
                        float sn, cs; sincosf((float)(row & 2047) * freq, &sn, &cs);
                        const float partner = __shfl_xor(v, 1);
                        v = (l16 & 1) ? fmaf(v, cs,  partner * sn)
                                      : fmaf(v, cs, -partner * sn);
                    }
                    dst[(size_t)row * 1024 + c] = f2b(v * scl);
                }
        }
    } else {
#pragma unroll
        for (int nt = 0; nt < NT; nt++) {
            const int col = n0 + wn + nt * 16 + l16;
#pragma unroll
            for (int mt = 0; mt < 4; mt++)
#pragma unroll
                for (int r = 0; r < 4; r++) {
                    const int row = m0 + wm + mt * 16 + quad * 4 + r;
                    Yf[(size_t)row * 1024 + col] = acc[mt][nt][r];
                }
        }
    }
}

// ---------------------------------------------------------------------------
// Flash causal attention, paired q-tiles (qtA, 31-qtA), unnormalized softmax
// (q pre-scaled 0.125*log2e -> p = exp2f(s)). K frags direct from global,
// prefetched. V staged coalesced (R8 pattern) into XOR-swizzled LDS
// transpose. XCD grouping: 16 blocks of one (b,h) share an XCD's L2.
// O aliases Q (block-disjoint regions).
// ---------------------------------------------------------------------------
__global__ __launch_bounds__(256, 2) void attn_kernel(
    const u16* Q, const u16* __restrict__ K,
    const u16* __restrict__ V, u16* O)
{
    __shared__ u16 Vt[64 * VSTR];           // Vt[d][s^((d>>4)<<4)]
    __shared__ u16 Ps[4 * 16 * VSTR];

    const int tid  = threadIdx.x;
    const int wave = tid >> 6;
    const int lane = tid & 63;
    const int quad = lane >> 4;
    const int l16  = lane & 15;
    // XCD grouping: g = slot*8 + xcd (round-robin heuristic); group G on xcd G&7
    const int g = blockIdx.x;
    const int xcd = g & 7, slot = g >> 3;
    const int G = (slot >> 4) * 8 + xcd;    // 0..31 = (b,h) group
    const int qtA = slot & 15;              // 0..15
    const int qtB = 31 - qtA;               // 31..16
    const int b = G & 1, h = G >> 1;
    const size_t base = ((size_t)b * 2048) * 1024 + (size_t)h * 64;

    short8 qfA[2], qfB[2];
    {
        const size_t ra = base + (size_t)(qtA * 64 + wave * 16 + l16) * 1024;
        qfA[0] = *reinterpret_cast<const short8*>(Q + ra + quad * 8);
        qfA[1] = *reinterpret_cast<const short8*>(Q + ra + 32 + quad * 8);
        const size_t rb = base + (size_t)(qtB * 64 + wave * 16 + l16) * 1024;
        qfB[0] = *reinterpret_cast<const short8*>(Q + rb + quad * 8);
        qfB[1] = *reinterpret_cast<const short8*>(Q + rb + 32 + quad * 8);
    }

    float4v oA[4], oB[4];
#pragma unroll
    for (int i = 0; i < 4; i++) { oA[i] = (float4v){0.f,0.f,0.f,0.f}; oB[i] = (float4v){0.f,0.f,0.f,0.f}; }
    float sA[4] = {0.f,0.f,0.f,0.f}, sB[4] = {0.f,0.f,0.f,0.f};

    u16* Pw = Ps + wave * 16 * VSTR;
    const int srow = tid >> 2;             // 0..63 (coalesced: 4 lanes/row)
    const int cb   = (tid & 3) << 4;       // 0,16,32,48
    const int sxw  = srow ^ cb;            // swizzled s ((d>>4)<<4 == cb)

    // prefetch tile j=0: V slab (coalesced) + K fragments (natural B layout)
    const u16* Vp = V + base + (size_t)srow * 1024 + cb;
    const u16* kbase = K + base + (size_t)l16 * 1024 + quad * 8;
    int4 vr0 = *reinterpret_cast<const int4*>(Vp);
    int4 vr1 = *reinterpret_cast<const int4*>(Vp + 8);
    short8 kn[4][2], kc[4][2], vf[4][2];
#pragma unroll
    for (int nt = 0; nt < 4; nt++)
#pragma unroll
        for (int ks = 0; ks < 2; ks++)
            kn[nt][ks] = *reinterpret_cast<const short8*>(kbase + (size_t)(nt * 16) * 1024 + ks * 32);

    auto proc = [&](const short8 (&qf)[2], float4v (&oc)[4], float (&sr)[4], bool diag) {
        float4v sacc[4];
#pragma unroll
        for (int nt = 0; nt < 4; nt++) {
            sacc[nt] = (float4v){0.f, 0.f, 0.f, 0.f};
#pragma unroll
            for (int ks = 0; ks < 2; ks++)
                sacc[nt] = __builtin_amdgcn_mfma_f32_16x16x32_bf16(qf[ks], kc[nt][ks], sacc[nt], 0, 0, 0);
        }
#pragma unroll
        for (int r = 0; r < 4; r++) {
            const int qloc = wave * 16 + quad * 4 + r;
#pragma unroll
            for (int nt = 0; nt < 4; nt++) {
                float s = sacc[nt][r];                       // log2-domain
                if (diag && (nt * 16 + l16 > qloc)) s = -1e30f;
                const float p = exp2f(s);                    // masked -> 0
                sr[r] += p;
                Pw[(quad * 4 + r) * VSTR + nt * 16 + l16] = f2b(p);
            }
        }
        __builtin_amdgcn_wave_barrier();   // P write->read is wave-local
#pragma unroll
        for (int ks = 0; ks < 2; ks++) {
            short8 pf = *reinterpret_cast<const short8*>(&Pw[l16 * VSTR + ks * 32 + quad * 8]);
#pragma unroll
            for (int dt = 0; dt < 4; dt++)
                oc[dt] = __builtin_amdgcn_mfma_f32_16x16x32_bf16(pf, vf[dt][ks], oc[dt], 0, 0, 0);
        }
        __builtin_amdgcn_wave_barrier();
    };

    for (int j = 0; j <= qtB; j++) {
        __syncthreads();   // all waves done reading previous Vt
        {
            const u16* a = reinterpret_cast<const u16*>(&vr0);   // V[srow][cb..+7]
            const u16* c = reinterpret_cast<const u16*>(&vr1);   // V[srow][cb+8..+15]
#pragma unroll
            for (int e = 0; e < 8; e++) Vt[(cb + e) * VSTR + sxw] = a[e];
#pragma unroll
            for (int e = 0; e < 8; e++) Vt[(cb + 8 + e) * VSTR + sxw] = c[e];
        }
#pragma unroll
        for (int nt = 0; nt < 4; nt++)
#pragma unroll
            for (int ks = 0; ks < 2; ks++) kc[nt][ks] = kn[nt][ks];
        __syncthreads();
        if (j < qtB) {     // prefetch tile j+1; latency hidden by procs
            Vp += 65536;
            vr0 = *reinterpret_cast<const int4*>(Vp);
            vr1 = *reinterpret_cast<const int4*>(Vp + 8);
            const u16* kb2 = kbase + (size_t)(j + 1) * 65536;
#pragma unroll
            for (int nt = 0; nt < 4; nt++)
#pragma unroll
                for (int ks = 0; ks < 2; ks++)
                    kn[nt][ks] = *reinterpret_cast<const short8*>(kb2 + (size_t)(nt * 16) * 1024 + ks * 32);
        }
#pragma unroll
        for (int nt = 0; nt < 4; nt++)
#pragma unroll
            for (int ks = 0; ks < 2; ks++)
                vf[nt][ks] = *reinterpret_cast<const short8*>(&Vt[(nt * 16 + l16) * VSTR + ((ks * 32 + quad * 8) ^ (nt << 4))]);
        if (j <= qtA) proc(qfA, oA, sA, j == qtA);
        proc(qfB, oB, sB, j == qtB);
    }

    // epilogue: one cross-lane sum reduction, normalize, write
#pragma unroll
    for (int r = 0; r < 4; r++) {
        float la = sA[r], lb = sB[r];
#pragma unroll
        for (int msk = 1; msk < 16; msk <<= 1) { la += __shfl_xor(la, msk); lb += __shfl_xor(lb, msk); }
        const float invA = 1.0f / la, invB = 1.0f / lb;
        const int rloc = wave * 16 + quad * 4 + r;
        const size_t rowA = base + (size_t)(qtA * 64 + rloc) * 1024;
        const size_t rowB = base + (size_t)(qtB * 64 + rloc) * 1024;
#pragma unroll
        for (int dt = 0; dt < 4; dt++) {
            O[rowA + dt * 16 + l16] = f2b(oA[dt][r] * invA);
            O[rowB + dt * 16 + l16] = f2b(oB[dt][r] * invB);
        }
    }
}

// ---------------------------------------------------------------------------
extern "C" void kernel_launch(void* const* d_in, const int* in_sizes, int n_in,
                              void* d_out, int out_size, void* d_ws, size_t ws_size,
                              hipStream_t stream) {
    (void)in_sizes; (void)n_in; (void)out_size; (void)ws_size;
    const float* x  = (const float*)d_in[0];
    const float* wq = (const float*)d_in[1];
    const float* wk = (const float*)d_in[2];
    const float* wv = (const float*)d_in[3];
    const float* wo = (const float*)d_in[4];

    const size_t MN = (size_t)4096 * 1024;

    // d_out (16MB) hosts xb (8MB) + wcat (6MB) until the final fp32 write.
    u16* xb   = (u16*)d_out;
    u16* wcat = xb + MN;                    // [3072][1024] = wq|wk|wv rows
    u16* qbuf = (u16*)d_ws;                 // also attention output
    u16* kbuf = qbuf + MN;
    u16* vbuf = kbuf + MN;
    u16* wob  = vbuf + MN;                  // ws total: 26MB

    cvt_all<<<4096, 256, 0, stream>>>((const float4*)x, (const float4*)wq,
                                      (const float4*)wk, (const float4*)wv,
                                      (const float4*)wo, xb, wcat, wob);
    gemm_tile<4, 1, 24><<<768, 256, 0, stream>>>(xb, wcat, qbuf, kbuf, vbuf, nullptr);
    attn_kernel<<<512, 256, 0, stream>>>(qbuf, kbuf, vbuf, qbuf);
    gemm_tile<2, 0, 16><<<512, 256, 0, stream>>>(qbuf, wob, nullptr, nullptr, nullptr, (float*)d_out);
}

// Round 11
// 228.542 us; speedup vs baseline: 1.0640x; 1.0227x over previous
//
#include <hip/hip_runtime.h>

// MHA forward, B=2, S=2048, D=1024, H=16, Dk=64, causal, RoPE. fp32 I/O.
// Internal bf16 MFMA 16x16x32, fp32 accum.
// R11: QKV epilogue was trig-bound (64 sincosf/thread ~ 2x the K-loop's MFMA
// cycles; VALUBusy 33% vs MfmaUtil 13%). RoPE cos/sin now precomputed into a
// 2048x32 float2 table (512KB, in d_out's free tail) by a tiny kernel using
// the identical exp2f+sincosf math; GEMM epilogue does one 8B load instead.

typedef unsigned short u16;
typedef __attribute__((ext_vector_type(8))) short short8;   // 8 bf16 = 4 VGPRs
typedef __attribute__((ext_vector_type(4))) float float4v;  // MFMA C/D

typedef const __attribute__((address_space(1))) void GV;    // global
typedef __attribute__((address_space(3))) void LV;          // LDS

#define VSTR 72   // attn Vt/Ps row stride (u16): 144B rows, 2-way read banks
#define QSCL 0.18033688011112042f   // 0.125 * log2(e)

__device__ __forceinline__ u16 f2b(float f) {
    union { float f; unsigned int i; } t; t.f = f;
    unsigned int r = t.i + 0x7fffu + ((t.i >> 16) & 1u);   // RNE
    return (u16)(r >> 16);
}

// ---------------- fused fp32 -> bf16 converter ------------------------------
__global__ __launch_bounds__(256) void cvt_all(
    const float4* __restrict__ x,  const float4* __restrict__ wq,
    const float4* __restrict__ wk, const float4* __restrict__ wv,
    const float4* __restrict__ wo,
    u16* __restrict__ xb, u16* __restrict__ wcat, u16* __restrict__ wob)
{
    const int i = blockIdx.x * 256 + threadIdx.x;
    const float4* s; u16* d; int off;
    if (i < 524288) { s = x; d = xb; off = i; }
    else {
        const int widx = i - 524288;
        const int w = widx >> 17, o = widx & 131071;
        switch (w) {
            case 0:  s = wq; d = wcat;              break;
            case 1:  s = wk; d = wcat + (1 << 20);  break;
            case 2:  s = wv; d = wcat + (2 << 20);  break;
            default: s = wo; d = wob;               break;
        }
        off = o;
    }
    float4 a = s[2 * off], b = s[2 * off + 1];
    u16 t[8] = {f2b(a.x), f2b(a.y), f2b(a.z), f2b(a.w),
                f2b(b.x), f2b(b.y), f2b(b.z), f2b(b.w)};
    reinterpret_cast<int4*>(d)[off] = *reinterpret_cast<int4*>(t);
}

// ---------------- RoPE cos/sin table: tab[pos*32+fi] = {cos, sin} ----------
__global__ __launch_bounds__(256) void rope_tab(float2* __restrict__ tab) {
    const int i = blockIdx.x * 256 + threadIdx.x;   // 0..65535
    const int pos = i >> 5, fi = i & 31;
    const float freq = exp2f((float)fi * -0.4152410118609203f);  // -log2(1e4)/32
    float sn, cs; sincosf((float)pos * freq, &sn, &cs);
    tab[i] = make_float2(cs, sn);
}

// ---------------------------------------------------------------------------
// Y[m][n] = sum_k X[m][k] * W[n][k]; 128(m) x NT*32(n) x 64(k) tiles.
// Staging: global_load_lds width=16. LDS: 64-elem rows, 16B unit u stored at
// phys u^(row&7) (lane-contiguous DMA dest, swizzled ds_read_b128).
// ROPE=1: route cols to Yq/Yk/Yv, RoPE q,k via table, scale q by QSCL.
// XCD swizzle: block g -> xcd=g&7 owns m-strips [xcd*4, xcd*4+4).
// ---------------------------------------------------------------------------
template<int NT, int ROPE, int NBLK>
__global__ __launch_bounds__(256) void gemm_tile(
    const u16* __restrict__ X, const u16* __restrict__ Wb,
    u16* __restrict__ Yq, u16* __restrict__ Yk, u16* __restrict__ Yv,
    float* __restrict__ Yf, const float2* __restrict__ tab)
{
    __shared__ u16 As[128 * 64];
    __shared__ u16 Bs[NT * 32 * 64];

    const int tid  = threadIdx.x;
    const int wave = tid >> 6;
    const int lane = tid & 63;
    const int quad = lane >> 4;
    const int l16  = lane & 15;
    const int wm = (wave >> 1) * 64, wn = (wave & 1) * (NT * 16);
    const int g = blockIdx.x;
    const int rr = g >> 3;
    const int m0 = ((g & 7) * 4 + rr / NBLK) * 128;
    const int n0 = (rr % NBLK) * (NT * 32);
    const int lrow = lane >> 3;                         // 0..7 within 8-row slab
    const int cg8  = (lane & 7) ^ lrow;                 // swizzled global unit

    float4v acc[4][NT];
#pragma unroll
    for (int mt = 0; mt < 4; mt++)
#pragma unroll
        for (int nt = 0; nt < NT; nt++) acc[mt][nt] = (float4v){0.f, 0.f, 0.f, 0.f};

    for (int kb = 0; kb < 1024; kb += 64) {
        __syncthreads();                                 // prev reads done
#pragma unroll
        for (int t = 0; t < 4; t++) {                    // stage A: 4x 1KB/wave
            const int I = wave * 4 + t;
            const u16* gp = X + (size_t)(m0 + I * 8 + lrow) * 1024 + kb + cg8 * 8;
            __builtin_amdgcn_global_load_lds((GV*)gp, (LV*)&As[I * 512], 16, 0, 0);
        }
#pragma unroll
        for (int t = 0; t < NT; t++) {                   // stage B: NTx 1KB/wave
            const int I = wave * NT + t;
            const u16* gp = Wb + (size_t)(n0 + I * 8 + lrow) * 1024 + kb + cg8 * 8;
            __builtin_amdgcn_global_load_lds((GV*)gp, (LV*)&Bs[I * 512], 16, 0, 0);
        }
        __syncthreads();                                 // vmcnt drained here
#pragma unroll
        for (int ks = 0; ks < 2; ks++) {
            const int su = ((ks * 4 + quad) ^ (l16 & 7)) * 8;   // swizzled unit
            short8 af[4], bf[NT];
#pragma unroll
            for (int t = 0; t < 4; t++)
                af[t] = *reinterpret_cast<const short8*>(&As[(wm + t * 16 + l16) * 64 + su]);
#pragma unroll
            for (int t = 0; t < NT; t++)
                bf[t] = *reinterpret_cast<const short8*>(&Bs[(wn + t * 16 + l16) * 64 + su]);
#pragma unroll
            for (int mt = 0; mt < 4; mt++)
#pragma unroll
                for (int nt = 0; nt < NT; nt++)
                    acc[mt][nt] = __builtin_amdgcn_mfma_f32_16x16x32_bf16(af[mt], bf[nt], acc[mt][nt], 0, 0, 0);
        }
    }

    if (ROPE) {
#pragma unroll
        for (int nt = 0; nt < NT; nt++) {
            const int cg = n0 + wn + nt * 16 + l16;      // global col 0..3071
            const int buf = cg >> 10;                    // 0=q 1=k 2=v
            const int c = cg & 1023;
            u16* dst = (buf == 0) ? Yq : ((buf == 1) ? Yk : Yv);
            const bool rp = (buf < 2);
            const float scl = (buf == 0) ? QSCL : 1.0f;
            const int fi = (cg & 63) >> 1;               // pair index in head
#pragma unroll
            for (int mt = 0; mt < 4; mt++)
#pragma unroll
                for (int r = 0; r < 4; r++) {
                    const int row = m0 + wm + mt * 16 + quad * 4 + r;
                    float v = acc[mt][nt][r];
                    if (rp) {
                        const float2 t = tab[((row & 2047) << 5) + fi];
                        const float partner = __shfl_xor(v, 1);
                        v = (l16 & 1) ? fmaf(v, t.x,  partner * t.y)
                                      : fmaf(v, t.x, -partner * t.y);
                    }
                    dst[(size_t)row * 1024 + c] = f2b(v * scl);
                }
        }
    } else {
#pragma unroll
        for (int nt = 0; nt < NT; nt++) {
            const int col = n0 + wn + nt * 16 + l16;
#pragma unroll
            for (int mt = 0; mt < 4; mt++)
#pragma unroll
                for (int r = 0; r < 4; r++) {
                    const int row = m0 + wm + mt * 16 + quad * 4 + r;
                    Yf[(size_t)row * 1024 + col] = acc[mt][nt][r];
                }
        }
    }
}

// ---------------------------------------------------------------------------
// Flash causal attention, paired q-tiles (qtA, 31-qtA), unnormalized softmax
// (q pre-scaled 0.125*log2e -> p = exp2f(s)). K frags direct from global,
// prefetched. V staged coalesced into XOR-swizzled LDS transpose. XCD
// grouping: 16 blocks of one (b,h) share an XCD's L2. O aliases Q.
// ---------------------------------------------------------------------------
__global__ __launch_bounds__(256, 2) void attn_kernel(
    const u16* Q, const u16* __restrict__ K,
    const u16* __restrict__ V, u16* O)
{
    __shared__ u16 Vt[64 * VSTR];           // Vt[d][s^((d>>4)<<4)]
    __shared__ u16 Ps[4 * 16 * VSTR];

    const int tid  = threadIdx.x;
    const int wave = tid >> 6;
    const int lane = tid & 63;
    const int quad = lane >> 4;
    const int l16  = lane & 15;
    const int g = blockIdx.x;
    const int xcd = g & 7, slot = g >> 3;
    const int G = (slot >> 4) * 8 + xcd;    // 0..31 = (b,h) group
    const int qtA = slot & 15;              // 0..15
    const int qtB = 31 - qtA;               // 31..16
    const int b = G & 1, h = G >> 1;
    const size_t base = ((size_t)b * 2048) * 1024 + (size_t)h * 64;

    short8 qfA[2], qfB[2];
    {
        const size_t ra = base + (size_t)(qtA * 64 + wave * 16 + l16) * 1024;
        qfA[0] = *reinterpret_cast<const short8*>(Q + ra + quad * 8);
        qfA[1] = *reinterpret_cast<const short8*>(Q + ra + 32 + quad * 8);
        const size_t rb = base + (size_t)(qtB * 64 + wave * 16 + l16) * 1024;
        qfB[0] = *reinterpret_cast<const short8*>(Q + rb + quad * 8);
        qfB[1] = *reinterpret_cast<const short8*>(Q + rb + 32 + quad * 8);
    }

    float4v oA[4], oB[4];
#pragma unroll
    for (int i = 0; i < 4; i++) { oA[i] = (float4v){0.f,0.f,0.f,0.f}; oB[i] = (float4v){0.f,0.f,0.f,0.f}; }
    float sA[4] = {0.f,0.f,0.f,0.f}, sB[4] = {0.f,0.f,0.f,0.f};

    u16* Pw = Ps + wave * 16 * VSTR;
    const int srow = tid >> 2;             // 0..63 (coalesced: 4 lanes/row)
    const int cb   = (tid & 3) << 4;       // 0,16,32,48
    const int sxw  = srow ^ cb;            // swizzled s ((d>>4)<<4 == cb)

    const u16* Vp = V + base + (size_t)srow * 1024 + cb;
    const u16* kbase = K + base + (size_t)l16 * 1024 + quad * 8;
    int4 vr0 = *reinterpret_cast<const int4*>(Vp);
    int4 vr1 = *reinterpret_cast<const int4*>(Vp + 8);
    short8 kn[4][2], kc[4][2], vf[4][2];
#pragma unroll
    for (int nt = 0; nt < 4; nt++)
#pragma unroll
        for (int ks = 0; ks < 2; ks++)
            kn[nt][ks] = *reinterpret_cast<const short8*>(kbase + (size_t)(nt * 16) * 1024 + ks * 32);

    auto proc = [&](const short8 (&qf)[2], float4v (&oc)[4], float (&sr)[4], bool diag) {
        float4v sacc[4];
#pragma unroll
        for (int nt = 0; nt < 4; nt++) {
            sacc[nt] = (float4v){0.f, 0.f, 0.f, 0.f};
#pragma unroll
            for (int ks = 0; ks < 2; ks++)
                sacc[nt] = __builtin_amdgcn_mfma_f32_16x16x32_bf16(qf[ks], kc[nt][ks], sacc[nt], 0, 0, 0);
        }
#pragma unroll
        for (int r = 0; r < 4; r++) {
            const int qloc = wave * 16 + quad * 4 + r;
#pragma unroll
            for (int nt = 0; nt < 4; nt++) {
                float s = sacc[nt][r];                       // log2-domain
                if (diag && (nt * 16 + l16 > qloc)) s = -1e30f;
                const float p = exp2f(s);                    // masked -> 0
                sr[r] += p;
                Pw[(quad * 4 + r) * VSTR + nt * 16 + l16] = f2b(p);
            }
        }
        __builtin_amdgcn_wave_barrier();   // P write->read is wave-local
#pragma unroll
        for (int ks = 0; ks < 2; ks++) {
            short8 pf = *reinterpret_cast<const short8*>(&Pw[l16 * VSTR + ks * 32 + quad * 8]);
#pragma unroll
            for (int dt = 0; dt < 4; dt++)
                oc[dt] = __builtin_amdgcn_mfma_f32_16x16x32_bf16(pf, vf[dt][ks], oc[dt], 0, 0, 0);
        }
        __builtin_amdgcn_wave_barrier();
    };

    for (int j = 0; j <= qtB; j++) {
        __syncthreads();   // all waves done reading previous Vt
        {
            const u16* a = reinterpret_cast<const u16*>(&vr0);   // V[srow][cb..+7]
            const u16* c = reinterpret_cast<const u16*>(&vr1);   // V[srow][cb+8..+15]
#pragma unroll
            for (int e = 0; e < 8; e++) Vt[(cb + e) * VSTR + sxw] = a[e];
#pragma unroll
            for (int e = 0; e < 8; e++) Vt[(cb + 8 + e) * VSTR + sxw] = c[e];
        }
#pragma unroll
        for (int nt = 0; nt < 4; nt++)
#pragma unroll
            for (int ks = 0; ks < 2; ks++) kc[nt][ks] = kn[nt][ks];
        __syncthreads();
        if (j < qtB) {     // prefetch tile j+1; latency hidden by procs
            Vp += 65536;
            vr0 = *reinterpret_cast<const int4*>(Vp);
            vr1 = *reinterpret_cast<const int4*>(Vp + 8);
            const u16* kb2 = kbase + (size_t)(j + 1) * 65536;
#pragma unroll
            for (int nt = 0; nt < 4; nt++)
#pragma unroll
                for (int ks = 0; ks < 2; ks++)
                    kn[nt][ks] = *reinterpret_cast<const short8*>(kb2 + (size_t)(nt * 16) * 1024 + ks * 32);
        }
#pragma unroll
        for (int nt = 0; nt < 4; nt++)
#pragma unroll
            for (int ks = 0; ks < 2; ks++)
                vf[nt][ks] = *reinterpret_cast<const short8*>(&Vt[(nt * 16 + l16) * VSTR + ((ks * 32 + quad * 8) ^ (nt << 4))]);
        if (j <= qtA) proc(qfA, oA, sA, j == qtA);
        proc(qfB, oB, sB, j == qtB);
    }

    // epilogue: one cross-lane sum reduction, normalize, write
#pragma unroll
    for (int r = 0; r < 4; r++) {
        float la = sA[r], lb = sB[r];
#pragma unroll
        for (int msk = 1; msk < 16; msk <<= 1) { la += __shfl_xor(la, msk); lb += __shfl_xor(lb, msk); }
        const float invA = 1.0f / la, invB = 1.0f / lb;
        const int rloc = wave * 16 + quad * 4 + r;
        const size_t rowA = base + (size_t)(qtA * 64 + rloc) * 1024;
        const size_t rowB = base + (size_t)(qtB * 64 + rloc) * 1024;
#pragma unroll
        for (int dt = 0; dt < 4; dt++) {
            O[rowA + dt * 16 + l16] = f2b(oA[dt][r] * invA);
            O[rowB + dt * 16 + l16] = f2b(oB[dt][r] * invB);
        }
    }
}

// ---------------------------------------------------------------------------
extern "C" void kernel_launch(void* const* d_in, const int* in_sizes, int n_in,
                              void* d_out, int out_size, void* d_ws, size_t ws_size,
                              hipStream_t stream) {
    (void)in_sizes; (void)n_in; (void)out_size; (void)ws_size;
    const float* x  = (const float*)d_in[0];
    const float* wq = (const float*)d_in[1];
    const float* wk = (const float*)d_in[2];
    const float* wv = (const float*)d_in[3];
    const float* wo = (const float*)d_in[4];

    const size_t MN = (size_t)4096 * 1024;

    // d_out (16MB): xb (8MB) + wcat (6MB) + rope table (512KB in free tail);
    // all consumed before the final fp32 GEMM overwrites d_out.
    u16* xb   = (u16*)d_out;
    u16* wcat = xb + MN;                    // [3072][1024] = wq|wk|wv rows
    float2* tab = (float2*)(wcat + (size_t)3072 * 1024);
    u16* qbuf = (u16*)d_ws;                 // also attention output
    u16* kbuf = qbuf + MN;
    u16* vbuf = kbuf + MN;
    u16* wob  = vbuf + MN;                  // ws total: 26MB

    cvt_all<<<4096, 256, 0, stream>>>((const float4*)x, (const float4*)wq,
                                      (const float4*)wk, (const float4*)wv,
                                      (const float4*)wo, xb, wcat, wob);
    rope_tab<<<256, 256, 0, stream>>>(tab);
    gemm_tile<4, 1, 24><<<768, 256, 0, stream>>>(xb, wcat, qbuf, kbuf, vbuf, nullptr, tab);
    attn_kernel<<<512, 256, 0, stream>>>(qbuf, kbuf, vbuf, qbuf);
    gemm_tile<2, 0, 16><<<512, 256, 0, stream>>>(qbuf, wob, nullptr, nullptr, nullptr, (float*)d_out, nullptr);
}